// Round 1
// baseline (415.357 us; speedup 1.0000x reference)
//
#include <hip/hip_runtime.h>

#define NROWS 524288
#define DDIM  64
#define HCENT 256
#define GRID  512
#define CPB   4   // 256-row chunks per block: 512*4*256 = 524288

typedef short bf16x8 __attribute__((ext_vector_type(8)));
typedef float f32x4  __attribute__((ext_vector_type(4)));

#define LOG2E 1.4426950408889634f
#define K2L   2.8853900817779268f   // 2*log2(e)
#define BIASF 80.0f

__device__ __forceinline__ float fast_exp2(float x) {
#if __has_builtin(__builtin_amdgcn_exp2f)
  return __builtin_amdgcn_exp2f(x);
#else
  return exp2f(x);
#endif
}

// Precompute per-center constants into workspace:
// cw[h]       = -(c2[h]*log2e + BIAS)
// cw[256 + h] = w[h]
__global__ __launch_bounds__(256) void rbf_setup(const float* __restrict__ centers,
                                                 const float* __restrict__ w,
                                                 float* __restrict__ cw) {
  int h = threadIdx.x;
  const float* cp = centers + h * DDIM;
  float s = 0.f;
#pragma unroll
  for (int d = 0; d < DDIM; ++d) s = fmaf(cp[d], cp[d], s);
  cw[h]         = -fmaf(s, LOG2E, BIASF);
  cw[HCENT + h] = w[h];
}

__global__ __launch_bounds__(256, 2) void rbf_main(const float* __restrict__ X,
                                                   const float* __restrict__ bptr,
                                                   const float* __restrict__ centers,
                                                   const float* __restrict__ cw,
                                                   float* __restrict__ out) {
  // Centers as split-bf16 MFMA B-fragments, fragment-ordered for conflict-free
  // ds_read_b128: index = (ct*2+kc)*64 + lane, 16B per lane. 32KB + 32KB.
  __shared__ int4 BH[16 * 2 * 64];
  __shared__ int4 BL[16 * 2 * 64];

  const int tid  = threadIdx.x;
  const int wave = tid >> 6;
  const int lane = tid & 63;
  const int q    = lane >> 4;   // k-group / row-quad
  const int c    = lane & 15;   // col within tile (and A-row at load)

  // ---- stage centers (once per block) ----
#pragma unroll
  for (int i = 0; i < 8; ++i) {
    int ct = wave + (i >> 1) * 4;
    int kc = i & 1;
    const float* src = centers + (ct * 16 + c) * DDIM + kc * 32 + q * 8;
    float4 f0 = reinterpret_cast<const float4*>(src)[0];
    float4 f1 = reinterpret_cast<const float4*>(src)[1];
    float xs[8] = {f0.x, f0.y, f0.z, f0.w, f1.x, f1.y, f1.z, f1.w};
    int hp[4], lp[4];
#pragma unroll
    for (int p = 0; p < 4; ++p) {
      unsigned u0 = __float_as_uint(xs[2 * p]);
      unsigned u1 = __float_as_uint(xs[2 * p + 1]);
      float l0 = xs[2 * p]     - __uint_as_float(u0 & 0xFFFF0000u);
      float l1 = xs[2 * p + 1] - __uint_as_float(u1 & 0xFFFF0000u);
      hp[p] = (int)((u1 & 0xFFFF0000u) | (u0 >> 16));
      lp[p] = (int)((__float_as_uint(l1) & 0xFFFF0000u) | (__float_as_uint(l0) >> 16));
    }
    int idx = (ct * 2 + kc) * 64 + lane;
    BH[idx] = make_int4(hp[0], hp[1], hp[2], hp[3]);
    BL[idx] = make_int4(lp[0], lp[1], lp[2], lp[3]);
  }

  // per-lane column constants (this lane always sees col = ct*16 + c)
  float mc[16], wl[16];
#pragma unroll
  for (int ct = 0; ct < 16; ++ct) {
    mc[ct] = cw[ct * 16 + c];
    wl[ct] = cw[HCENT + ct * 16 + c];
  }
  float bval = bptr[0];

  __syncthreads();  // LDS read-only hereafter; no barrier in the sweep loop

  for (int s = 0; s < CPB; ++s) {
    int rowbase = (blockIdx.x * CPB + s) * 256 + wave * 64;

    // ---- load X rows, split to bf16 hi/lo A-fragments, compute x2 ----
    bf16x8 ah[4][2], al[4][2];
    float x2l[4][4];
#pragma unroll
    for (int rt = 0; rt < 4; ++rt) {
      const float* rp = X + (rowbase + rt * 16 + c) * DDIM + q * 8;
      float part = 0.f;
#pragma unroll
      for (int kc = 0; kc < 2; ++kc) {
        float4 f0 = reinterpret_cast<const float4*>(rp + kc * 32)[0];
        float4 f1 = reinterpret_cast<const float4*>(rp + kc * 32)[1];
        float xs[8] = {f0.x, f0.y, f0.z, f0.w, f1.x, f1.y, f1.z, f1.w};
        union { int i[4]; bf16x8 v; } uh, ul;
#pragma unroll
        for (int p = 0; p < 4; ++p) {
          float x0 = xs[2 * p], x1 = xs[2 * p + 1];
          part = fmaf(x0, x0, part);
          part = fmaf(x1, x1, part);
          unsigned u0 = __float_as_uint(x0);
          unsigned u1 = __float_as_uint(x1);
          float l0 = x0 - __uint_as_float(u0 & 0xFFFF0000u);
          float l1 = x1 - __uint_as_float(u1 & 0xFFFF0000u);
          uh.i[p] = (int)((u1 & 0xFFFF0000u) | (u0 >> 16));
          ul.i[p] = (int)((__float_as_uint(l1) & 0xFFFF0000u) | (__float_as_uint(l0) >> 16));
        }
        ah[rt][kc] = uh.v;
        al[rt][kc] = ul.v;
      }
      // full-row x2: sum partials across the 4 k-groups
      part += __shfl_xor(part, 16, 64);
      part += __shfl_xor(part, 32, 64);
      // redistribute to C-layout rows (row = q*4 + r held by lane q*4+r, <16)
#pragma unroll
      for (int r = 0; r < 4; ++r)
        x2l[rt][r] = __shfl(part, q * 4 + r, 64);
    }

    // ---- sweep 16 col-tiles ----
    float psum[4][4] = {{0.f}};
    for (int ct = 0; ct < 16; ++ct) {
      const bf16x8* BHv = reinterpret_cast<const bf16x8*>(BH);
      const bf16x8* BLv = reinterpret_cast<const bf16x8*>(BL);
      int idx = ct * 128 + lane;
      bf16x8 bh0 = BHv[idx], bh1 = BHv[idx + 64];
      bf16x8 bl0 = BLv[idx], bl1 = BLv[idx + 64];
#pragma unroll
      for (int rt = 0; rt < 4; ++rt) {
        f32x4 acc = {0.f, 0.f, 0.f, 0.f};
        acc = __builtin_amdgcn_mfma_f32_16x16x32_bf16(ah[rt][0], bh0, acc, 0, 0, 0);
        acc = __builtin_amdgcn_mfma_f32_16x16x32_bf16(ah[rt][1], bh1, acc, 0, 0, 0);
        acc = __builtin_amdgcn_mfma_f32_16x16x32_bf16(al[rt][0], bh0, acc, 0, 0, 0);
        acc = __builtin_amdgcn_mfma_f32_16x16x32_bf16(al[rt][1], bh1, acc, 0, 0, 0);
        acc = __builtin_amdgcn_mfma_f32_16x16x32_bf16(ah[rt][0], bl0, acc, 0, 0, 0);
        acc = __builtin_amdgcn_mfma_f32_16x16x32_bf16(ah[rt][1], bl1, acc, 0, 0, 0);
        // epilogue: contribution = exp2(2L*a - (L*c2+B)) * w, row factor later
#pragma unroll
        for (int r = 0; r < 4; ++r) {
          float e = fast_exp2(fmaf(acc[r], K2L, mc[ct]));
          psum[rt][r] = fmaf(e, wl[ct], psum[rt][r]);
        }
      }
    }

    // ---- reduce over the 16 col-lanes, apply row factor, store ----
#pragma unroll
    for (int rt = 0; rt < 4; ++rt) {
#pragma unroll
      for (int r = 0; r < 4; ++r) {
        float v = psum[rt][r];
        v += __shfl_xor(v, 1, 64);
        v += __shfl_xor(v, 2, 64);
        v += __shfl_xor(v, 4, 64);
        v += __shfl_xor(v, 8, 64);
        float rowf = fast_exp2(fmaf(-LOG2E, x2l[rt][r], BIASF));
        psum[rt][r] = fmaf(v, rowf, bval);
      }
      if (c == 0) {
        float4 o = make_float4(psum[rt][0], psum[rt][1], psum[rt][2], psum[rt][3]);
        *reinterpret_cast<float4*>(out + rowbase + rt * 16 + q * 4) = o;
      }
    }
  }
}

extern "C" void kernel_launch(void* const* d_in, const int* in_sizes, int n_in,
                              void* d_out, int out_size, void* d_ws, size_t ws_size,
                              hipStream_t stream) {
  const float* X       = (const float*)d_in[0];
  const float* centers = (const float*)d_in[1];
  const float* w       = (const float*)d_in[2];
  const float* b       = (const float*)d_in[3];
  float* out = (float*)d_out;
  float* cw  = (float*)d_ws;   // 512 floats

  rbf_setup<<<1, 256, 0, stream>>>(centers, w, cw);
  rbf_main<<<GRID, 256, 0, stream>>>(X, b, centers, cw, out);
}

// Round 2
// 348.871 us; speedup vs baseline: 1.1906x; 1.1906x over previous
//
#include <hip/hip_runtime.h>

#define NROWS 524288
#define DDIM  64
#define HCENT 256
#define GRID  512
#define CPB   8   // 128-row chunks per block: 512*8*128 = 524288

typedef short bf16x8 __attribute__((ext_vector_type(8)));
typedef float f32x4  __attribute__((ext_vector_type(4)));

#define LOG2E 1.4426950408889634f
#define K2L   2.8853900817779268f   // 2*log2(e)
#define BIASF 80.0f

__device__ __forceinline__ float fast_exp2(float x) {
#if __has_builtin(__builtin_amdgcn_exp2f)
  return __builtin_amdgcn_exp2f(x);
#else
  return exp2f(x);
#endif
}

// Precompute per-center constants into workspace:
// cw[h]       = -(c2[h]*log2e + BIAS)
// cw[256 + h] = w[h]
__global__ __launch_bounds__(256) void rbf_setup(const float* __restrict__ centers,
                                                 const float* __restrict__ w,
                                                 float* __restrict__ cw) {
  int h = threadIdx.x;
  const float* cp = centers + h * DDIM;
  float s = 0.f;
#pragma unroll
  for (int d = 0; d < DDIM; ++d) s = fmaf(cp[d], cp[d], s);
  cw[h]         = -fmaf(s, LOG2E, BIASF);
  cw[HCENT + h] = w[h];
}

__global__ __launch_bounds__(256, 2) void rbf_main(const float* __restrict__ X,
                                                   const float* __restrict__ bptr,
                                                   const float* __restrict__ centers,
                                                   const float* __restrict__ cw,
                                                   float* __restrict__ out) {
  // Centers as split-bf16 MFMA B-fragments, fragment-ordered for conflict-free
  // ds_read_b128: index = (ct*2+kc)*64 + lane, 16B per lane. 32KB + 32KB = 64KB
  // exactly (2 blocks/CU). cw stays in global: 2KB working set, L1-resident.
  __shared__ int4 BH[16 * 2 * 64];
  __shared__ int4 BL[16 * 2 * 64];

  const int tid  = threadIdx.x;
  const int wave = tid >> 6;
  const int lane = tid & 63;
  const int q    = lane >> 4;   // k-group / row-quad
  const int c    = lane & 15;   // col within tile (and A-row at load)

  // ---- stage centers (once per block) ----
#pragma unroll
  for (int i = 0; i < 8; ++i) {
    int ct = wave + (i >> 1) * 4;
    int kc = i & 1;
    const float* src = centers + (ct * 16 + c) * DDIM + kc * 32 + q * 8;
    float4 f0 = reinterpret_cast<const float4*>(src)[0];
    float4 f1 = reinterpret_cast<const float4*>(src)[1];
    float xs[8] = {f0.x, f0.y, f0.z, f0.w, f1.x, f1.y, f1.z, f1.w};
    int hp[4], lp[4];
#pragma unroll
    for (int p = 0; p < 4; ++p) {
      unsigned u0 = __float_as_uint(xs[2 * p]);
      unsigned u1 = __float_as_uint(xs[2 * p + 1]);
      float l0 = xs[2 * p]     - __uint_as_float(u0 & 0xFFFF0000u);
      float l1 = xs[2 * p + 1] - __uint_as_float(u1 & 0xFFFF0000u);
      hp[p] = (int)((u1 & 0xFFFF0000u) | (u0 >> 16));
      lp[p] = (int)((__float_as_uint(l1) & 0xFFFF0000u) | (__float_as_uint(l0) >> 16));
    }
    int idx = (ct * 2 + kc) * 64 + lane;
    BH[idx] = make_int4(hp[0], hp[1], hp[2], hp[3]);
    BL[idx] = make_int4(lp[0], lp[1], lp[2], lp[3]);
  }

  float bval = bptr[0];
  const float* mcp = cw + c;          // mc for this lane's col, + ct*16
  const float* wlp = cw + HCENT + c;  // w  for this lane's col, + ct*16

  __syncthreads();  // LDS read-only hereafter; no barrier in the sweep loop

  const bf16x8* BHv = reinterpret_cast<const bf16x8*>(BH);
  const bf16x8* BLv = reinterpret_cast<const bf16x8*>(BL);

  for (int s = 0; s < CPB; ++s) {
    int rowbase = (blockIdx.x * CPB + s) * 128 + wave * 32;

    // ---- load X rows, split to bf16 hi/lo A-fragments, compute x2 ----
    bf16x8 ah[2][2], al[2][2];
    float x2p[2];
#pragma unroll
    for (int rt = 0; rt < 2; ++rt) {
      const float* rp = X + (rowbase + rt * 16 + c) * DDIM + q * 8;
      float part = 0.f;
#pragma unroll
      for (int kc = 0; kc < 2; ++kc) {
        float4 f0 = reinterpret_cast<const float4*>(rp + kc * 32)[0];
        float4 f1 = reinterpret_cast<const float4*>(rp + kc * 32)[1];
        float xs[8] = {f0.x, f0.y, f0.z, f0.w, f1.x, f1.y, f1.z, f1.w};
        union { int i[4]; bf16x8 v; } uh, ul;
#pragma unroll
        for (int p = 0; p < 4; ++p) {
          float x0 = xs[2 * p], x1 = xs[2 * p + 1];
          part = fmaf(x0, x0, part);
          part = fmaf(x1, x1, part);
          unsigned u0 = __float_as_uint(x0);
          unsigned u1 = __float_as_uint(x1);
          float l0 = x0 - __uint_as_float(u0 & 0xFFFF0000u);
          float l1 = x1 - __uint_as_float(u1 & 0xFFFF0000u);
          uh.i[p] = (int)((u1 & 0xFFFF0000u) | (u0 >> 16));
          ul.i[p] = (int)((__float_as_uint(l1) & 0xFFFF0000u) | (__float_as_uint(l0) >> 16));
        }
        ah[rt][kc] = uh.v;
        al[rt][kc] = ul.v;
      }
      // full-row x2: sum partials across the 4 k-groups (replicated in all q)
      part += __shfl_xor(part, 16, 64);
      part += __shfl_xor(part, 32, 64);
      x2p[rt] = part;   // lane with c==r holds x2 of row rt*16+r
    }

    // ---- sweep 16 col-tiles ----
    float psum[2][4] = {{0.f, 0.f, 0.f, 0.f}, {0.f, 0.f, 0.f, 0.f}};
    for (int ct = 0; ct < 16; ++ct) {
      int idx = ct * 128 + lane;
      bf16x8 bh0 = BHv[idx], bh1 = BHv[idx + 64];
      bf16x8 bl0 = BLv[idx], bl1 = BLv[idx + 64];
      float mcv = mcp[ct * 16];   // -(c2*log2e + BIAS), L1-resident
      float wlv = wlp[ct * 16];   // w, L1-resident
#pragma unroll
      for (int rt = 0; rt < 2; ++rt) {
        f32x4 acc = {0.f, 0.f, 0.f, 0.f};
        acc = __builtin_amdgcn_mfma_f32_16x16x32_bf16(ah[rt][0], bh0, acc, 0, 0, 0);
        acc = __builtin_amdgcn_mfma_f32_16x16x32_bf16(ah[rt][1], bh1, acc, 0, 0, 0);
        acc = __builtin_amdgcn_mfma_f32_16x16x32_bf16(al[rt][0], bh0, acc, 0, 0, 0);
        acc = __builtin_amdgcn_mfma_f32_16x16x32_bf16(al[rt][1], bh1, acc, 0, 0, 0);
        acc = __builtin_amdgcn_mfma_f32_16x16x32_bf16(ah[rt][0], bl0, acc, 0, 0, 0);
        acc = __builtin_amdgcn_mfma_f32_16x16x32_bf16(ah[rt][1], bl1, acc, 0, 0, 0);
        // epilogue: contribution = exp2(2L*a - (L*c2+B)) * w, row factor later
#pragma unroll
        for (int r = 0; r < 4; ++r) {
          float e = fast_exp2(fmaf(acc[r], K2L, mcv));
          psum[rt][r] = fmaf(e, wlv, psum[rt][r]);
        }
      }
    }

    // ---- reduce over the 16 col-lanes, apply row factor, store ----
#pragma unroll
    for (int rt = 0; rt < 2; ++rt) {
#pragma unroll
      for (int r = 0; r < 4; ++r) {
        float v = psum[rt][r];
        v += __shfl_xor(v, 1, 64);
        v += __shfl_xor(v, 2, 64);
        v += __shfl_xor(v, 4, 64);
        v += __shfl_xor(v, 8, 64);
        // x2 of row q*4+r lives in lanes with c == q*4+r (replicated over q)
        float x2row = __shfl(x2p[rt], q * 4 + r, 64);
        float rowf = fast_exp2(fmaf(-LOG2E, x2row, BIASF));
        psum[rt][r] = fmaf(v, rowf, bval);
      }
      if (c == 0) {
        float4 o = make_float4(psum[rt][0], psum[rt][1], psum[rt][2], psum[rt][3]);
        *reinterpret_cast<float4*>(out + rowbase + rt * 16 + q * 4) = o;
      }
    }
  }
}

extern "C" void kernel_launch(void* const* d_in, const int* in_sizes, int n_in,
                              void* d_out, int out_size, void* d_ws, size_t ws_size,
                              hipStream_t stream) {
  const float* X       = (const float*)d_in[0];
  const float* centers = (const float*)d_in[1];
  const float* w       = (const float*)d_in[2];
  const float* b       = (const float*)d_in[3];
  float* out = (float*)d_out;
  float* cw  = (float*)d_ws;   // 512 floats

  rbf_setup<<<1, 256, 0, stream>>>(centers, w, cw);
  rbf_main<<<GRID, 256, 0, stream>>>(X, b, centers, cw, out);
}

// Round 3
// 210.458 us; speedup vs baseline: 1.9736x; 1.6577x over previous
//
#include <hip/hip_runtime.h>

#define NROWS 524288
#define DDIM  64
#define HCENT 256
#define GRID  512
#define CPB   4   // 256-row chunks per block: 512*4*256 = 524288

typedef short bf16x8 __attribute__((ext_vector_type(8)));
typedef float f32x4  __attribute__((ext_vector_type(4)));

#define LOG2E 1.4426950408889634f
#define K2L   2.8853900817779268f   // 2*log2(e)
#define BIASF 80.0f

__device__ __forceinline__ float fast_exp2(float x) {
#if __has_builtin(__builtin_amdgcn_exp2f)
  return __builtin_amdgcn_exp2f(x);
#else
  return exp2f(x);
#endif
}

// Precompute per-center constants into workspace, interleaved:
// cw[2h]   = -(c2[h]*log2e + BIAS)
// cw[2h+1] = w[h]
__global__ __launch_bounds__(256) void rbf_setup(const float* __restrict__ centers,
                                                 const float* __restrict__ w,
                                                 float* __restrict__ cw) {
  int h = threadIdx.x;
  const float* cp = centers + h * DDIM;
  float s = 0.f;
#pragma unroll
  for (int d = 0; d < DDIM; ++d) s = fmaf(cp[d], cp[d], s);
  cw[2 * h]     = -fmaf(s, LOG2E, BIASF);
  cw[2 * h + 1] = w[h];
}

__global__ __launch_bounds__(512, 4) void rbf_main(const float* __restrict__ X,
                                                   const float* __restrict__ bptr,
                                                   const float* __restrict__ centers,
                                                   const float* __restrict__ cw,
                                                   float* __restrict__ out) {
  // Centers as split-bf16 MFMA B-fragments, fragment-ordered for conflict-free
  // ds_read_b128: index = (ct*2+kc)*64 + lane, 16B per lane. 32KB+32KB+2KB=66KB
  // -> 2 blocks/CU (block=512 => 16 waves/CU, 4 waves/EU).
  __shared__ int4 BH[16 * 2 * 64];
  __shared__ int4 BL[16 * 2 * 64];
  __shared__ float2 CWs[HCENT];   // (mc, w) per center

  const int tid  = threadIdx.x;
  const int wave = tid >> 6;      // 0..7
  const int lane = tid & 63;
  const int q    = lane >> 4;     // k-group / row-quad
  const int c    = lane & 15;     // col within tile (and A-row at load)

  // ---- stage centers (once per block; 8 waves x 4 (ct,kc) pairs) ----
#pragma unroll
  for (int i = 0; i < 4; ++i) {
    int pair = wave * 4 + i;      // 0..31
    int ct = pair >> 1;
    int kc = pair & 1;
    const float* src = centers + (ct * 16 + c) * DDIM + kc * 32 + q * 8;
    float4 f0 = reinterpret_cast<const float4*>(src)[0];
    float4 f1 = reinterpret_cast<const float4*>(src)[1];
    float xs[8] = {f0.x, f0.y, f0.z, f0.w, f1.x, f1.y, f1.z, f1.w};
    int hp[4], lp[4];
#pragma unroll
    for (int p = 0; p < 4; ++p) {
      unsigned u0 = __float_as_uint(xs[2 * p]);
      unsigned u1 = __float_as_uint(xs[2 * p + 1]);
      float l0 = xs[2 * p]     - __uint_as_float(u0 & 0xFFFF0000u);
      float l1 = xs[2 * p + 1] - __uint_as_float(u1 & 0xFFFF0000u);
      hp[p] = (int)((u1 & 0xFFFF0000u) | (u0 >> 16));
      lp[p] = (int)((__float_as_uint(l1) & 0xFFFF0000u) | (__float_as_uint(l0) >> 16));
    }
    int idx = pair * 64 + lane;
    BH[idx] = make_int4(hp[0], hp[1], hp[2], hp[3]);
    BL[idx] = make_int4(lp[0], lp[1], lp[2], lp[3]);
  }
  // stage cw: 512 threads -> 512 floats
  reinterpret_cast<float*>(CWs)[tid] = cw[tid];

  float bval = bptr[0];

  __syncthreads();  // LDS read-only hereafter; no barrier in the sweep loop

  const bf16x8* BHv = reinterpret_cast<const bf16x8*>(BH);
  const bf16x8* BLv = reinterpret_cast<const bf16x8*>(BL);

#pragma unroll 1
  for (int s = 0; s < CPB; ++s) {
    int rowbase = (blockIdx.x * CPB + s) * 256 + wave * 32;

    // ---- load X rows, split to bf16 hi/lo A-fragments, partial x2 ----
    bf16x8 ah[2][2], al[2][2];
    float x2p[2];
#pragma unroll
    for (int rt = 0; rt < 2; ++rt) {
      const float* rp = X + (rowbase + rt * 16 + c) * DDIM + q * 8;
      float part = 0.f;
#pragma unroll
      for (int kc = 0; kc < 2; ++kc) {
        float4 f0 = reinterpret_cast<const float4*>(rp + kc * 32)[0];
        float4 f1 = reinterpret_cast<const float4*>(rp + kc * 32)[1];
        float xs[8] = {f0.x, f0.y, f0.z, f0.w, f1.x, f1.y, f1.z, f1.w};
        union { int i[4]; bf16x8 v; } uh, ul;
#pragma unroll
        for (int p = 0; p < 4; ++p) {
          float x0 = xs[2 * p], x1 = xs[2 * p + 1];
          part = fmaf(x0, x0, part);
          part = fmaf(x1, x1, part);
          unsigned u0 = __float_as_uint(x0);
          unsigned u1 = __float_as_uint(x1);
          float l0 = x0 - __uint_as_float(u0 & 0xFFFF0000u);
          float l1 = x1 - __uint_as_float(u1 & 0xFFFF0000u);
          uh.i[p] = (int)((u1 & 0xFFFF0000u) | (u0 >> 16));
          ul.i[p] = (int)((__float_as_uint(l1) & 0xFFFF0000u) | (__float_as_uint(l0) >> 16));
        }
        ah[rt][kc] = uh.v;
        al[rt][kc] = ul.v;
      }
      x2p[rt] = part;   // k-partial; cross-k shfl deferred to epilogue
    }

    // ---- sweep 16 col-tiles ----
    float psum[2][4] = {{0.f, 0.f, 0.f, 0.f}, {0.f, 0.f, 0.f, 0.f}};
#pragma unroll 2
    for (int ct = 0; ct < 16; ++ct) {
      int idx = ct * 128 + lane;
      bf16x8 bh0 = BHv[idx], bh1 = BHv[idx + 64];
      bf16x8 bl0 = BLv[idx], bl1 = BLv[idx + 64];
      float2 mw = CWs[ct * 16 + c];   // (mc, w) via ds_read_b64, broadcast over q
#pragma unroll
      for (int rt = 0; rt < 2; ++rt) {
        f32x4 acc = {0.f, 0.f, 0.f, 0.f};
        acc = __builtin_amdgcn_mfma_f32_16x16x32_bf16(ah[rt][0], bh0, acc, 0, 0, 0);
        acc = __builtin_amdgcn_mfma_f32_16x16x32_bf16(ah[rt][1], bh1, acc, 0, 0, 0);
        acc = __builtin_amdgcn_mfma_f32_16x16x32_bf16(al[rt][0], bh0, acc, 0, 0, 0);
        acc = __builtin_amdgcn_mfma_f32_16x16x32_bf16(al[rt][1], bh1, acc, 0, 0, 0);
        acc = __builtin_amdgcn_mfma_f32_16x16x32_bf16(ah[rt][0], bl0, acc, 0, 0, 0);
        acc = __builtin_amdgcn_mfma_f32_16x16x32_bf16(ah[rt][1], bl1, acc, 0, 0, 0);
        // contribution = exp2(2L*a - (L*c2+B)) * w; row factor applied later
#pragma unroll
        for (int r = 0; r < 4; ++r) {
          float e = fast_exp2(fmaf(acc[r], K2L, mw.x));
          psum[rt][r] = fmaf(e, mw.y, psum[rt][r]);
        }
      }
    }

    // ---- reduce over the 16 col-lanes, apply row factor, store ----
#pragma unroll
    for (int rt = 0; rt < 2; ++rt) {
      // complete x2 across k-groups now (off the sweep's critical path)
      float part = x2p[rt];
      part += __shfl_xor(part, 16, 64);
      part += __shfl_xor(part, 32, 64);
#pragma unroll
      for (int r = 0; r < 4; ++r) {
        float v = psum[rt][r];
        v += __shfl_xor(v, 1, 64);
        v += __shfl_xor(v, 2, 64);
        v += __shfl_xor(v, 4, 64);
        v += __shfl_xor(v, 8, 64);
        // x2 of row q*4+r lives in lanes with c == q*4+r (replicated over q)
        float x2row = __shfl(part, q * 4 + r, 64);
        float rowf = fast_exp2(fmaf(-LOG2E, x2row, BIASF));
        psum[rt][r] = fmaf(v, rowf, bval);
      }
      if (c == 0) {
        float4 o = make_float4(psum[rt][0], psum[rt][1], psum[rt][2], psum[rt][3]);
        *reinterpret_cast<float4*>(out + rowbase + rt * 16 + q * 4) = o;
      }
    }
  }
}

extern "C" void kernel_launch(void* const* d_in, const int* in_sizes, int n_in,
                              void* d_out, int out_size, void* d_ws, size_t ws_size,
                              hipStream_t stream) {
  const float* X       = (const float*)d_in[0];
  const float* centers = (const float*)d_in[1];
  const float* w       = (const float*)d_in[2];
  const float* b       = (const float*)d_in[3];
  float* out = (float*)d_out;
  float* cw  = (float*)d_ws;   // 512 floats, interleaved (mc, w)

  rbf_setup<<<1, 256, 0, stream>>>(centers, w, cw);
  rbf_main<<<GRID, 512, 0, stream>>>(X, b, centers, cw, out);
}